// Round 5
// baseline (176.588 us; speedup 1.0000x reference)
//
#include <hip/hip_runtime.h>
#include <stdint.h>

#define D_MODEL 1024
#define NHEADS 16
#define HDIM 64
#define BATCH 2
#define SEQ 2048
#define MTOK (BATCH*SEQ)

typedef unsigned short u16;
typedef __attribute__((ext_vector_type(8))) __bf16 bf16x8;
typedef __attribute__((ext_vector_type(8))) unsigned short u16x8;
typedef __attribute__((ext_vector_type(4))) unsigned short u16x4;
typedef __attribute__((ext_vector_type(4))) float f32x4;
typedef __attribute__((ext_vector_type(2))) float f32x2;

__device__ __forceinline__ u16 f2bf(float f) {
  union { float f; uint32_t u; } v; v.f = f;
  uint32_t u = v.u;
  u += 0x7fffu + ((u >> 16) & 1u);   // RNE
  return (u16)(u >> 16);
}

__device__ __forceinline__ u16 f2bf_hw(float f) {
  return __builtin_bit_cast(u16, (__bf16)f);   // v_cvt, RNE
}

__device__ __forceinline__ f32x4 max4(f32x4 a, f32x4 b) {
  f32x4 r;
  r[0]=fmaxf(a[0],b[0]); r[1]=fmaxf(a[1],b[1]);
  r[2]=fmaxf(a[2],b[2]); r[3]=fmaxf(a[3],b[3]);
  return r;
}

__device__ __forceinline__ void async16(u16* lds, const u16* g) {
  __builtin_amdgcn_global_load_lds(
      (__attribute__((address_space(1))) void*)(u16*)g,
      (__attribute__((address_space(3))) void*)lds,
      16, 0, 0);
}

// ---------------- cast f32 -> bf16 (vectorized) ----------------
__global__ __launch_bounds__(256) void cast_bf16_kernel(
    const float* __restrict__ in, u16* __restrict__ out, int n8)
{
  int i = blockIdx.x * 256 + threadIdx.x;
  if (i >= n8) return;
  const float4* p = (const float4*)(in + (size_t)i * 8);
  float4 a = p[0], b = p[1];
  u16x8 r;
  r[0]=f2bf(a.x); r[1]=f2bf(a.y); r[2]=f2bf(a.z); r[3]=f2bf(a.w);
  r[4]=f2bf(b.x); r[5]=f2bf(b.y); r[6]=f2bf(b.z); r[7]=f2bf(b.w);
  *(u16x8*)(out + (size_t)i * 8) = r;
}

// ---------------- transpose+cast f32 [R][C] -> bf16 [C][R] ----------------
__global__ __launch_bounds__(256) void transpose_cast_kernel(
    const float* __restrict__ in, u16* __restrict__ out, int R, int C)
{
  __shared__ float tile[32][33];
  int nCB = C >> 5;
  int bc = blockIdx.x % nCB, br = blockIdx.x / nCB;
  int r0 = br * 32, c0 = bc * 32;
  int tx = threadIdx.x & 31, ty = threadIdx.x >> 5;
#pragma unroll
  for (int i = 0; i < 4; ++i)
    tile[ty + i*8][tx] = in[(size_t)(r0 + ty + i*8) * C + c0 + tx];
  __syncthreads();
#pragma unroll
  for (int i = 0; i < 4; ++i)
    out[(size_t)(c0 + ty + i*8) * R + r0 + tx] = f2bf(tile[tx][ty + i*8]);
}

// ---------------- transpose bf16 V [bh][2048][64] -> [bh][64][2048] ----------------
__global__ __launch_bounds__(256) void transpose_v_kernel(
    const u16* __restrict__ vb, u16* __restrict__ vt)
{
  __shared__ u16 tile[32][34];
  int b = blockIdx.x >> 7;      // 0..31 (b*H+h)
  int t = blockIdx.x & 127;
  int br = t >> 1, bc = t & 1;
  int r0 = br * 32, c0 = bc * 32;
  const u16* in = vb + (size_t)b * SEQ * HDIM;
  u16* out = vt + (size_t)b * SEQ * HDIM;
  int tx = threadIdx.x & 31, ty = threadIdx.x >> 5;
#pragma unroll
  for (int i = 0; i < 4; ++i)
    tile[ty + i*8][tx] = in[(size_t)(r0 + ty + i*8) * HDIM + c0 + tx];
  __syncthreads();
#pragma unroll
  for (int i = 0; i < 4; ++i)
    out[(size_t)(c0 + ty + i*8) * SEQ + r0 + tx] = tile[tx][ty + i*8];
}

// ---------------- NT GEMM: C[M][N] = A[M][K](bf16) * Bt[N][K](bf16)^T + bias ----------------
// EPI=0: QKV epilogue -> scatter q(*scale*log2e)/k/v into [B,H,N,Hd] bf16
// EPI=1: f32 out
template <int EPI>
__global__ __launch_bounds__(256) void gemm_bt_kernel(
    const u16* __restrict__ A, const u16* __restrict__ Bt,
    const float* __restrict__ bias,
    float* __restrict__ outF,
    u16* __restrict__ qb, u16* __restrict__ kb, u16* __restrict__ vb,
    int M, int Nn, int K)
{
  __shared__ alignas(16) u16 As[128 * 64];
  __shared__ alignas(16) u16 Bs[128 * 64];

  const int tid = threadIdx.x;
  const int wid = tid >> 6, lane = tid & 63;
  const int col = lane & 15, kg = lane >> 4;

  const int nTN = Nn >> 7;
  int bidx = blockIdx.x;
  {
    int cpx = gridDim.x >> 3;     // grid % 8 == 0 for all our launches
    bidx = (bidx & 7) * cpx + (bidx >> 3);
  }
  const int tile_m = (bidx / nTN) << 7;
  const int tile_n = (bidx % nTN) << 7;
  const int wm = (wid >> 1) << 6, wn = (wid & 1) << 6;

  f32x4 acc[4][4] = {};

  const int sr = tid >> 3;          // 0..31
  const int sc = (tid & 7) << 3;    // 0..56

  for (int kt = 0; kt < K; kt += 64) {
    __syncthreads();
#pragma unroll
    for (int i = 0; i < 4; ++i)
      async16(&As[(i*32 + sr) * 64 + sc],
              A + (size_t)(tile_m + i*32 + sr) * K + kt + sc);
#pragma unroll
    for (int i = 0; i < 4; ++i)
      async16(&Bs[(i*32 + sr) * 64 + sc],
              Bt + (size_t)(tile_n + i*32 + sr) * K + kt + sc);
    __syncthreads();

#pragma unroll
    for (int ks = 0; ks < 2; ++ks) {
      bf16x8 af[4], bfv[4];
#pragma unroll
      for (int i = 0; i < 4; ++i)
        af[i] = *(const bf16x8*)&As[(wm + i*16 + col) * 64 + ks*32 + kg*8];
#pragma unroll
      for (int i = 0; i < 4; ++i)
        bfv[i] = *(const bf16x8*)&Bs[(wn + i*16 + col) * 64 + ks*32 + kg*8];
#pragma unroll
      for (int i = 0; i < 4; ++i)
#pragma unroll
        for (int j = 0; j < 4; ++j)
          acc[i][j] = __builtin_amdgcn_mfma_f32_16x16x32_bf16(af[i], bfv[j], acc[i][j], 0, 0, 0);
    }
  }

  // epilogue: lane holds C[tile_m+wm+i*16+kg*4+j][tile_n+wn+jn*16+col]
#pragma unroll
  for (int i = 0; i < 4; ++i) {
#pragma unroll
    for (int jn = 0; jn < 4; ++jn) {
      const int gcol = tile_n + wn + jn*16 + col;
      const float bv = bias[gcol];
#pragma unroll
      for (int j = 0; j < 4; ++j) {
        const int grow = tile_m + wm + i*16 + kg*4 + j;
        float val = acc[i][jn][j] + bv;
        if (EPI == 1) {
          outF[(size_t)grow * Nn + gcol] = val;
        } else {
          int btok = grow >> 11, tok = grow & 2047;
          int which = gcol >> 10, f = gcol & 1023;
          int h = f >> 6, hd = f & 63;
          size_t dst = ((size_t)(btok * NHEADS + h) * SEQ + tok) * HDIM + hd;
          // fold scale = Hd^-0.5 * log2(e) into Q (softmax runs in exp2 domain)
          if (which == 0)      qb[dst] = f2bf(val * 0.18033688f);
          else if (which == 1) kb[dst] = f2bf(val);
          else                 vb[dst] = f2bf(val);
        }
      }
    }
  }
}

// ---------------- flash attention: KV-split 2-way, XOR-swizzled LDS, 32q/wave ----------------
// block = (b*H+h, q-tile 128, kv-half); 4 waves x 32 q-rows; KVBLK = 64.
// Swapped softmax (S^T = K·Q^T), exp2 domain. All LDS tiles pitch-64 u16 with
// elem ^= (row&7)<<3 XOR swizzle -> <=2-way bank conflicts. Partial numerator
// (f32) + (m,l) written to workspace; combine_kernel merges the two halves.
__global__ __launch_bounds__(256, 4) void attn_kernel(
    const u16* __restrict__ qb, const u16* __restrict__ kb,
    const u16* __restrict__ vt, float* __restrict__ on, f32x2* __restrict__ ml)
{
  __shared__ alignas(16) u16 Ks[64 * 64];     // [kv][hd] swizzled
  __shared__ alignas(16) u16 Vs[64 * 64];     // [hd][kv] swizzled
  __shared__ alignas(16) u16 Pl[4][32 * 64];  // per-wave P [q][kv] swizzled

  const int tid = threadIdx.x, wid = tid >> 6, lane = tid & 63;
  const int col = lane & 15, kg = lane >> 4;
  const int csw = (col & 7) << 3;

  int bidx = blockIdx.x;
  bidx = (bidx & 7) * 128 + (bidx >> 3);   // XCD swizzle (grid 1024)
  const int bh   = bidx >> 5;      // 0..31  (4 bh per XCD -> K/V L2-resident)
  const int qt   = (bidx >> 1) & 15;
  const int half = bidx & 1;

  const u16* Qh = qb + (size_t)bh * SEQ * HDIM;
  const u16* Kh = kb + (size_t)bh * SEQ * HDIM;
  const u16* Vh = vt + (size_t)bh * SEQ * HDIM;  // [64][2048]

  const int q0 = qt * 128 + wid * 32;
  // Q as B-operand: lane holds Q[q = mf*16+col][d = ks*32+kg*8 .. +7]
  bf16x8 qf[2][2];
#pragma unroll
  for (int mf = 0; mf < 2; ++mf)
#pragma unroll
    for (int ks = 0; ks < 2; ++ks)
      qf[mf][ks] = *(const bf16x8*)(Qh + (size_t)(q0 + mf*16 + col) * HDIM + ks*32 + kg*8);

  float m_run[2] = {-1e30f, -1e30f};
  float l_run[2] = {0.f, 0.f};
  f32x4 o[2][4] = {};   // O^T[hd = hf*16+kg*4+j][q = mf*16+col]

  u16* Pw = Pl[wid];

  // staging: thread covers 32B of K tile row sr and V^T tile row sr
  const int sr = tid >> 2;            // 0..63
  const int sc = (tid & 3) << 4;      // 0,16,32,48 (u16 units)
  const int ssw = (sr & 7) << 3;

  u16x8 kreg[2], vreg[2];
#define LOAD_TILES(t)                                                          \
  {                                                                            \
    _Pragma("unroll")                                                          \
    for (int i = 0; i < 2; ++i)                                                \
      kreg[i] = *(const u16x8*)(Kh + (size_t)((t)*64 + sr) * HDIM + sc + i*8); \
    _Pragma("unroll")                                                          \
    for (int i = 0; i < 2; ++i)                                                \
      vreg[i] = *(const u16x8*)(Vh + (size_t)sr * SEQ + (t)*64 + sc + i*8);    \
  }

  const int t0 = half * 16;
  LOAD_TILES(t0);

  for (int t = t0; t < t0 + 16; ++t) {
    __syncthreads();   // previous tile's LDS reads done
#pragma unroll
    for (int i = 0; i < 2; ++i)
      *(u16x8*)&Ks[sr * 64 + ((sc + i*8) ^ ssw)] = kreg[i];
#pragma unroll
    for (int i = 0; i < 2; ++i)
      *(u16x8*)&Vs[sr * 64 + ((sc + i*8) ^ ssw)] = vreg[i];
    __syncthreads();
    if (t < t0 + 15) LOAD_TILES(t + 1);   // latency hides under compute below

    // S^T = K Q^T : s[mf][nf] rows k = nf*16+kg*4+r, col q = mf*16+col
    f32x4 s[2][4] = {};
#pragma unroll
    for (int ks = 0; ks < 2; ++ks) {
#pragma unroll
      for (int nf = 0; nf < 4; ++nf) {
        bf16x8 kf = *(const bf16x8*)&Ks[(nf*16 + col) * 64 + ((ks*32 + kg*8) ^ csw)];
        s[0][nf] = __builtin_amdgcn_mfma_f32_16x16x32_bf16(kf, qf[0][ks], s[0][nf], 0, 0, 0);
        s[1][nf] = __builtin_amdgcn_mfma_f32_16x16x32_bf16(kf, qf[1][ks], s[1][nf], 0, 0, 0);
      }
    }

    // online softmax (exp2 domain), lane-local per q
#pragma unroll
    for (int mf = 0; mf < 2; ++mf) {
      f32x4 u0 = max4(max4(s[mf][0], s[mf][1]), max4(s[mf][2], s[mf][3]));
      float mx = fmaxf(fmaxf(u0[0], u0[1]), fmaxf(u0[2], u0[3]));
      mx = fmaxf(mx, __shfl_xor(mx, 16));
      mx = fmaxf(mx, __shfl_xor(mx, 32));
      float mo = m_run[mf];
      float mn = fmaxf(mo, mx);
      float al = __builtin_amdgcn_exp2f(mo - mn);
      m_run[mf] = mn;
      f32x4 sum4 = {0.f, 0.f, 0.f, 0.f};
#pragma unroll
      for (int nf = 0; nf < 4; ++nf) {
#pragma unroll
        for (int r = 0; r < 4; ++r)
          s[mf][nf][r] = __builtin_amdgcn_exp2f(s[mf][nf][r] - mn);
        sum4[0] += s[mf][nf][0]; sum4[1] += s[mf][nf][1];
        sum4[2] += s[mf][nf][2]; sum4[3] += s[mf][nf][3];
      }
      float sum = (sum4[0] + sum4[1]) + (sum4[2] + sum4[3]);
      sum += __shfl_xor(sum, 16);
      sum += __shfl_xor(sum, 32);
      l_run[mf] = l_run[mf] * al + sum;
#pragma unroll
      for (int hf = 0; hf < 4; ++hf)
#pragma unroll
        for (int j = 0; j < 4; ++j) o[mf][hf][j] *= al;
      // pack P -> LDS: P[q = mf*16+col][k = nf*16+kg*4 .. +3]
#pragma unroll
      for (int nf = 0; nf < 4; ++nf) {
        u16x4 pk;
        pk[0] = f2bf_hw(s[mf][nf][0]); pk[1] = f2bf_hw(s[mf][nf][1]);
        pk[2] = f2bf_hw(s[mf][nf][2]); pk[3] = f2bf_hw(s[mf][nf][3]);
        *(u16x4*)&Pw[(mf*16 + col) * 64 + ((nf*16 + kg*4) ^ csw)] = pk;
      }
    }

    // O^T += V^T P^T
#pragma unroll
    for (int ks = 0; ks < 2; ++ks) {
      bf16x8 pf0 = *(const bf16x8*)&Pw[(col) * 64 + ((ks*32 + kg*8) ^ csw)];
      bf16x8 pf1 = *(const bf16x8*)&Pw[(16 + col) * 64 + ((ks*32 + kg*8) ^ csw)];
#pragma unroll
      for (int hf = 0; hf < 4; ++hf) {
        bf16x8 vf = *(const bf16x8*)&Vs[(hf*16 + col) * 64 + ((ks*32 + kg*8) ^ csw)];
        o[0][hf] = __builtin_amdgcn_mfma_f32_16x16x32_bf16(vf, pf0, o[0][hf], 0, 0, 0);
        o[1][hf] = __builtin_amdgcn_mfma_f32_16x16x32_bf16(vf, pf1, o[1][hf], 0, 0, 0);
      }
    }
  }

  // epilogue: partial numerator O^T (f32) + (m,l) to workspace
  const int bb = bh >> 4, h = bh & 15;
  float* onH = on + (size_t)half * MTOK * D_MODEL;
#pragma unroll
  for (int mf = 0; mf < 2; ++mf) {
    int tok = bb * SEQ + q0 + mf*16 + col;
#pragma unroll
    for (int hf = 0; hf < 4; ++hf)
      *(f32x4*)&onH[(size_t)tok * D_MODEL + h*64 + hf*16 + kg*4] = o[mf][hf];
    if (kg == 0) {
      f32x2 v; v[0] = m_run[mf]; v[1] = l_run[mf];
      ml[(size_t)half * NHEADS*2*SEQ + (size_t)bh * SEQ + q0 + mf*16 + col] = v;
    }
  }
#undef LOAD_TILES
}

// ---------------- combine the two KV-halves ----------------
__global__ __launch_bounds__(256) void combine_kernel(
    const float* __restrict__ on, const f32x2* __restrict__ ml,
    u16* __restrict__ ao)
{
  int idx = blockIdx.x * 256 + threadIdx.x;   // 1M threads, 4 feats each
  int tok = idx >> 8;
  int f4  = (idx & 255) << 2;
  int h   = f4 >> 6;
  int bh  = ((tok >> 11) << 4) + h;
  int q   = tok & 2047;
  f32x2 ml0 = ml[(size_t)bh * SEQ + q];
  f32x2 ml1 = ml[(size_t)NHEADS*2*SEQ + (size_t)bh * SEQ + q];
  float M  = fmaxf(ml0[0], ml1[0]);
  float a0 = __builtin_amdgcn_exp2f(ml0[0] - M);
  float a1 = __builtin_amdgcn_exp2f(ml1[0] - M);
  float inv = 1.0f / (a0 * ml0[1] + a1 * ml1[1]);
  float4 o0 = *(const float4*)&on[(size_t)tok * D_MODEL + f4];
  float4 o1 = *(const float4*)&on[(size_t)MTOK * D_MODEL + (size_t)tok * D_MODEL + f4];
  u16x4 pk;
  pk[0] = f2bf((a0*o0.x + a1*o1.x) * inv);
  pk[1] = f2bf((a0*o0.y + a1*o1.y) * inv);
  pk[2] = f2bf((a0*o0.z + a1*o1.z) * inv);
  pk[3] = f2bf((a0*o0.w + a1*o1.w) * inv);
  *(u16x4*)&ao[(size_t)tok * D_MODEL + f4] = pk;
}

extern "C" void kernel_launch(void* const* d_in, const int* in_sizes, int n_in,
                              void* d_out, int out_size, void* d_ws, size_t ws_size,
                              hipStream_t stream)
{
  const float* x     = (const float*)d_in[0];
  const float* w_qkv = (const float*)d_in[1];
  const float* b_qkv = (const float*)d_in[2];
  const float* w_out = (const float*)d_in[3];
  const float* b_out = (const float*)d_in[4];
  float* out = (float*)d_out;
  (void)in_sizes; (void)n_in; (void)out_size; (void)ws_size;

  char* ws = (char*)d_ws;
  u16*   qb     = (u16*)(ws);                        //  0-8   [32][2048][64]
  u16*   kb     = (u16*)(ws + (size_t)( 8 << 20));   //  8-16
  u16*   vt     = (u16*)(ws + (size_t)(16 << 20));   // 16-24  [32][64][2048]
  u16*   ao     = (u16*)(ws + (size_t)(24 << 20));   // 24-32  [4096][1024]
  u16*   wout_t = (u16*)(ws + (size_t)(32 << 20));   // 32-34
  u16*   x_bf   = (u16*)(ws + (size_t)(40 << 20));   // 40-48  dead after gemm0
  u16*   wqkv_t = (u16*)(ws + (size_t)(48 << 20));   // 48-54  dead after gemm0
  u16*   vb     = (u16*)(ws + (size_t)(56 << 20));   // 56-64  dead after transpose_v
  float* on     = (float*)(ws + (size_t)(40 << 20)); // 40-72  overlays the dead regions
  f32x2* ml     = (f32x2*)(ws + (size_t)(72 << 20)); // 72-73

  cast_bf16_kernel<<<2048, 256, 0, stream>>>(x, x_bf, (MTOK * D_MODEL) / 8);
  transpose_cast_kernel<<<(1024/32)*(3072/32), 256, 0, stream>>>(w_qkv, wqkv_t, 1024, 3072);
  transpose_cast_kernel<<<(1024/32)*(1024/32), 256, 0, stream>>>(w_out, wout_t, 1024, 1024);

  gemm_bt_kernel<0><<<(MTOK/128)*(3072/128), 256, 0, stream>>>(
      x_bf, wqkv_t, b_qkv, nullptr, qb, kb, vb, MTOK, 3072, 1024);

  transpose_v_kernel<<<32*128, 256, 0, stream>>>(vb, vt);

  attn_kernel<<<32*16*2, 256, 0, stream>>>(qb, kb, vt, on, ml);

  combine_kernel<<<(MTOK*D_MODEL/4)/256, 256, 0, stream>>>(on, ml, ao);

  gemm_bt_kernel<1><<<(MTOK/128)*(1024/128), 256, 0, stream>>>(
      ao, wout_t, b_out, out, nullptr, nullptr, nullptr, MTOK, 1024, 1024);
}

// Round 6
// 146.602 us; speedup vs baseline: 1.2045x; 1.2045x over previous
//
#include <hip/hip_runtime.h>
#include <stdint.h>

#define D_MODEL 1024
#define NHEADS 16
#define HDIM 64
#define BATCH 2
#define SEQ 2048
#define MTOK (BATCH*SEQ)

typedef unsigned short u16;
typedef __attribute__((ext_vector_type(8))) __bf16 bf16x8;
typedef __attribute__((ext_vector_type(8))) unsigned short u16x8;
typedef __attribute__((ext_vector_type(4))) unsigned short u16x4;
typedef __attribute__((ext_vector_type(4))) float f32x4;

__device__ __forceinline__ u16 f2bf(float f) {
  union { float f; uint32_t u; } v; v.f = f;
  uint32_t u = v.u;
  u += 0x7fffu + ((u >> 16) & 1u);   // RNE
  return (u16)(u >> 16);
}

__device__ __forceinline__ u16 f2bf_hw(float f) {
  return __builtin_bit_cast(u16, (__bf16)f);   // v_cvt, RNE
}

__device__ __forceinline__ f32x4 max4(f32x4 a, f32x4 b) {
  f32x4 r;
  r[0]=fmaxf(a[0],b[0]); r[1]=fmaxf(a[1],b[1]);
  r[2]=fmaxf(a[2],b[2]); r[3]=fmaxf(a[3],b[3]);
  return r;
}

__device__ __forceinline__ void async16(u16* lds, const u16* g) {
  __builtin_amdgcn_global_load_lds(
      (__attribute__((address_space(1))) void*)(u16*)g,
      (__attribute__((address_space(3))) void*)lds,
      16, 0, 0);
}

// ---------------- fused prep: cast x; transpose+cast w_qkv, w_out ----------------
__device__ __forceinline__ void transpose_cast_body(
    const float* __restrict__ in, u16* __restrict__ out, int R, int C,
    int bid, int tid, float (*tile)[33])
{
  int nCB = C >> 5;
  int bc = bid % nCB, br = bid / nCB;
  int r0 = br * 32, c0 = bc * 32;
  int tx = tid & 31, ty = tid >> 5;
#pragma unroll
  for (int i = 0; i < 4; ++i)
    tile[ty + i*8][tx] = in[(size_t)(r0 + ty + i*8) * C + c0 + tx];
  __syncthreads();
#pragma unroll
  for (int i = 0; i < 4; ++i)
    out[(size_t)(c0 + ty + i*8) * R + r0 + tx] = f2bf(tile[tx][ty + i*8]);
}

__global__ __launch_bounds__(256) void prep_kernel(
    const float* __restrict__ x, const float* __restrict__ w_qkv,
    const float* __restrict__ w_out,
    u16* __restrict__ x_bf, u16* __restrict__ wqkv_t, u16* __restrict__ wout_t)
{
  __shared__ float tile[32][33];
  int bid = blockIdx.x, tid = threadIdx.x;
  if (bid < 2048) {
    int i = bid * 256 + tid;           // 8 bf16 per thread
    const float4* p = (const float4*)(x + (size_t)i * 8);
    float4 a = p[0], b = p[1];
    u16x8 r;
    r[0]=f2bf(a.x); r[1]=f2bf(a.y); r[2]=f2bf(a.z); r[3]=f2bf(a.w);
    r[4]=f2bf(b.x); r[5]=f2bf(b.y); r[6]=f2bf(b.z); r[7]=f2bf(b.w);
    *(u16x8*)(x_bf + (size_t)i * 8) = r;
  } else if (bid < 2048 + 3072) {
    transpose_cast_body(w_qkv, wqkv_t, 1024, 3072, bid - 2048, tid, tile);
  } else {
    transpose_cast_body(w_out, wout_t, 1024, 1024, bid - 5120, tid, tile);
  }
}

// ---------------- NT GEMM: C[M][N] = A[M][K](bf16) * Bt[N][K](bf16)^T + bias ----------------
// EPI=0: QKV epilogue -> scatter q(*scale*log2e)/k into [B,H,N,Hd], V transposed
//        directly into vt[B,H,Hd,N] (u16x4-packed over 4 consecutive tokens)
// EPI=1: f32 out
template <int EPI>
__global__ __launch_bounds__(256) void gemm_bt_kernel(
    const u16* __restrict__ A, const u16* __restrict__ Bt,
    const float* __restrict__ bias,
    float* __restrict__ outF,
    u16* __restrict__ qb, u16* __restrict__ kb, u16* __restrict__ vt,
    int M, int Nn, int K)
{
  __shared__ alignas(16) u16 As[128 * 64];
  __shared__ alignas(16) u16 Bs[128 * 64];

  const int tid = threadIdx.x;
  const int wid = tid >> 6, lane = tid & 63;
  const int col = lane & 15, kg = lane >> 4;

  const int nTN = Nn >> 7;
  int bidx = blockIdx.x;
  {
    int cpx = gridDim.x >> 3;     // grid % 8 == 0 for all our launches
    bidx = (bidx & 7) * cpx + (bidx >> 3);
  }
  const int tile_m = (bidx / nTN) << 7;
  const int tile_n = (bidx % nTN) << 7;
  const int wm = (wid >> 1) << 6, wn = (wid & 1) << 6;

  f32x4 acc[4][4] = {};

  const int sr = tid >> 3;          // 0..31
  const int sc = (tid & 7) << 3;    // 0..56

  for (int kt = 0; kt < K; kt += 64) {
    __syncthreads();
#pragma unroll
    for (int i = 0; i < 4; ++i)
      async16(&As[(i*32 + sr) * 64 + sc],
              A + (size_t)(tile_m + i*32 + sr) * K + kt + sc);
#pragma unroll
    for (int i = 0; i < 4; ++i)
      async16(&Bs[(i*32 + sr) * 64 + sc],
              Bt + (size_t)(tile_n + i*32 + sr) * K + kt + sc);
    __syncthreads();

#pragma unroll
    for (int ks = 0; ks < 2; ++ks) {
      bf16x8 af[4], bfv[4];
#pragma unroll
      for (int i = 0; i < 4; ++i)
        af[i] = *(const bf16x8*)&As[(wm + i*16 + col) * 64 + ks*32 + kg*8];
#pragma unroll
      for (int i = 0; i < 4; ++i)
        bfv[i] = *(const bf16x8*)&Bs[(wn + i*16 + col) * 64 + ks*32 + kg*8];
#pragma unroll
      for (int i = 0; i < 4; ++i)
#pragma unroll
        for (int j = 0; j < 4; ++j)
          acc[i][j] = __builtin_amdgcn_mfma_f32_16x16x32_bf16(af[i], bfv[j], acc[i][j], 0, 0, 0);
    }
  }

  // epilogue: lane holds C[tile_m+wm+i*16+kg*4+j][tile_n+wn+jn*16+col]
#pragma unroll
  for (int i = 0; i < 4; ++i) {
#pragma unroll
    for (int jn = 0; jn < 4; ++jn) {
      const int gcol = tile_n + wn + jn*16 + col;
      const float bv = bias[gcol];
      const int grow0 = tile_m + wm + i*16 + kg*4;   // 4-aligned, no 2048-cross
      if (EPI == 1) {
#pragma unroll
        for (int j = 0; j < 4; ++j)
          outF[(size_t)(grow0 + j) * Nn + gcol] = acc[i][jn][j] + bv;
      } else {
        const int btok = grow0 >> 11, tok0 = grow0 & 2047;
        const int which = gcol >> 10, f = gcol & 1023;
        const int h = f >> 6, hd = f & 63;
        if (which == 2) {
          // V transposed: vt[(btok*16+h)*64+hd][tok0..tok0+3], one 8B store
          u16x4 pk;
#pragma unroll
          for (int j = 0; j < 4; ++j) pk[j] = f2bf(acc[i][jn][j] + bv);
          *(u16x4*)&vt[((size_t)(btok*NHEADS + h) * HDIM + hd) * SEQ + tok0] = pk;
        } else {
#pragma unroll
          for (int j = 0; j < 4; ++j) {
            float val = acc[i][jn][j] + bv;
            size_t dst = ((size_t)(btok*NHEADS + h) * SEQ + tok0 + j) * HDIM + hd;
            // fold scale = Hd^-0.5 * log2(e) into Q (softmax in exp2 domain)
            if (which == 0) qb[dst] = f2bf(val * 0.18033688f);
            else            kb[dst] = f2bf(val);
          }
        }
      }
    }
  }
}

// ---------------- flash attention: KVBLK=128, XOR-swizzled LDS, reg-prefetch ----------------
// block = (b*H+h, q-tile of 128); 4 waves x 32 q-rows; 16 KV tiles of 128.
// Swapped softmax (S^T = K·Q^T), exp2 domain (scale*log2e folded into Q).
// All LDS tiles XOR-swizzled (elem ^= (row&7)<<3) -> <=2-way conflicts.
// K/V tile t+1 prefetched into registers during compute of tile t.
__global__ __launch_bounds__(256, 2) void attn_kernel(
    const u16* __restrict__ qb, const u16* __restrict__ kb,
    const u16* __restrict__ vt, u16* __restrict__ ao)
{
  __shared__ alignas(16) u16 Ks[128 * 64];     // [kv][hd] swizzled
  __shared__ alignas(16) u16 Vs[64 * 128];     // [hd][kv] swizzled
  __shared__ alignas(16) u16 Pl[4][32 * 128];  // per-wave P [q][kv] swizzled

  const int tid = threadIdx.x, wid = tid >> 6, lane = tid & 63;
  const int col = lane & 15, kg = lane >> 4;
  const int csw = (col & 7) << 3;

  int bidx = blockIdx.x;
  bidx = (bidx & 7) * 64 + (bidx >> 3);   // XCD swizzle (grid 512)
  const int bh = bidx >> 4;     // 0..31
  const int qt = bidx & 15;

  const u16* Qh = qb + (size_t)bh * SEQ * HDIM;
  const u16* Kh = kb + (size_t)bh * SEQ * HDIM;
  const u16* Vh = vt + (size_t)bh * SEQ * HDIM;  // [64][2048]

  const int q0 = qt * 128 + wid * 32;
  // Q as B-operand: lane holds Q[q = mf*16+col][d = ks*32+kg*8 .. +7]
  bf16x8 qf[2][2];
#pragma unroll
  for (int mf = 0; mf < 2; ++mf)
#pragma unroll
    for (int ks = 0; ks < 2; ++ks)
      qf[mf][ks] = *(const bf16x8*)(Qh + (size_t)(q0 + mf*16 + col) * HDIM + ks*32 + kg*8);

  float m_run[2] = {-1e30f, -1e30f};
  float l_run[2] = {0.f, 0.f};
  f32x4 o[2][4] = {};   // O^T[hd = hf*16+kg*4+j][q = mf*16+col]

  u16* Pw = Pl[wid];

  // staging geometry: K tile [128][64] -> thread owns row tid>>1, half (tid&1)*32
  //                   V^T tile [64][128] -> thread owns row tid>>2, quarter (tid&3)*32
  const int krow = tid >> 1, kc = (tid & 1) << 5, ksw = (krow & 7) << 3;
  const int vrow = tid >> 2, vc = (tid & 3) << 5, vsw = (vrow & 7) << 3;

  u16x8 kreg[4], vreg[4];
#define LOAD_TILES(t)                                                               \
  {                                                                                 \
    _Pragma("unroll")                                                               \
    for (int i = 0; i < 4; ++i)                                                     \
      kreg[i] = *(const u16x8*)(Kh + (size_t)((t)*128 + krow) * HDIM + kc + i*8);   \
    _Pragma("unroll")                                                               \
    for (int i = 0; i < 4; ++i)                                                     \
      vreg[i] = *(const u16x8*)(Vh + (size_t)vrow * SEQ + (t)*128 + vc + i*8);      \
  }

  LOAD_TILES(0);

  for (int t = 0; t < 16; ++t) {
    __syncthreads();   // previous tile's LDS reads done
#pragma unroll
    for (int i = 0; i < 4; ++i)
      *(u16x8*)&Ks[krow * 64 + ((kc + i*8) ^ ksw)] = kreg[i];
#pragma unroll
    for (int i = 0; i < 4; ++i)
      *(u16x8*)&Vs[vrow * 128 + ((vc + i*8) ^ vsw)] = vreg[i];
    __syncthreads();
    if (t < 15) LOAD_TILES(t + 1);   // latency hides under compute below

    // S^T = K Q^T : s[mf][nf] rows k = nf*16+kg*4+r, col q = mf*16+col
    f32x4 s[2][8] = {};
#pragma unroll
    for (int ks = 0; ks < 2; ++ks) {
#pragma unroll
      for (int nf = 0; nf < 8; ++nf) {
        bf16x8 kf = *(const bf16x8*)&Ks[(nf*16 + col) * 64 + ((ks*32 + kg*8) ^ csw)];
        s[0][nf] = __builtin_amdgcn_mfma_f32_16x16x32_bf16(kf, qf[0][ks], s[0][nf], 0, 0, 0);
        s[1][nf] = __builtin_amdgcn_mfma_f32_16x16x32_bf16(kf, qf[1][ks], s[1][nf], 0, 0, 0);
      }
    }

    // online softmax (exp2 domain), lane-local per q
#pragma unroll
    for (int mf = 0; mf < 2; ++mf) {
      f32x4 t0 = max4(s[mf][0], s[mf][1]);
      f32x4 t1 = max4(s[mf][2], s[mf][3]);
      f32x4 t2 = max4(s[mf][4], s[mf][5]);
      f32x4 t3 = max4(s[mf][6], s[mf][7]);
      f32x4 u0 = max4(max4(t0, t1), max4(t2, t3));
      float mx = fmaxf(fmaxf(u0[0], u0[1]), fmaxf(u0[2], u0[3]));
      mx = fmaxf(mx, __shfl_xor(mx, 16));
      mx = fmaxf(mx, __shfl_xor(mx, 32));
      float mo = m_run[mf];
      float mn = fmaxf(mo, mx);
      float al = __builtin_amdgcn_exp2f(mo - mn);
      m_run[mf] = mn;
      f32x4 sum4 = {0.f, 0.f, 0.f, 0.f};
#pragma unroll
      for (int nf = 0; nf < 8; ++nf) {
#pragma unroll
        for (int r = 0; r < 4; ++r)
          s[mf][nf][r] = __builtin_amdgcn_exp2f(s[mf][nf][r] - mn);
        sum4[0] += s[mf][nf][0]; sum4[1] += s[mf][nf][1];
        sum4[2] += s[mf][nf][2]; sum4[3] += s[mf][nf][3];
      }
      float sum = (sum4[0] + sum4[1]) + (sum4[2] + sum4[3]);
      sum += __shfl_xor(sum, 16);
      sum += __shfl_xor(sum, 32);
      l_run[mf] = l_run[mf] * al + sum;
#pragma unroll
      for (int hf = 0; hf < 4; ++hf)
#pragma unroll
        for (int j = 0; j < 4; ++j) o[mf][hf][j] *= al;
      // pack P -> LDS: P[q = mf*16+col][k = nf*16+kg*4 .. +3]
#pragma unroll
      for (int nf = 0; nf < 8; ++nf) {
        u16x4 pk;
        pk[0] = f2bf_hw(s[mf][nf][0]); pk[1] = f2bf_hw(s[mf][nf][1]);
        pk[2] = f2bf_hw(s[mf][nf][2]); pk[3] = f2bf_hw(s[mf][nf][3]);
        *(u16x4*)&Pw[(mf*16 + col) * 128 + ((nf*16 + kg*4) ^ csw)] = pk;
      }
    }

    // O^T += V^T P^T
#pragma unroll
    for (int ks = 0; ks < 4; ++ks) {
      bf16x8 pf0 = *(const bf16x8*)&Pw[(col) * 128 + ((ks*32 + kg*8) ^ csw)];
      bf16x8 pf1 = *(const bf16x8*)&Pw[(16 + col) * 128 + ((ks*32 + kg*8) ^ csw)];
#pragma unroll
      for (int hf = 0; hf < 4; ++hf) {
        bf16x8 vf = *(const bf16x8*)&Vs[(hf*16 + col) * 128 + ((ks*32 + kg*8) ^ csw)];
        o[0][hf] = __builtin_amdgcn_mfma_f32_16x16x32_bf16(vf, pf0, o[0][hf], 0, 0, 0);
        o[1][hf] = __builtin_amdgcn_mfma_f32_16x16x32_bf16(vf, pf1, o[1][hf], 0, 0, 0);
      }
    }
  }

  // epilogue: O^T/l -> ao[token][h*64+hd] bf16 (lane-local l), b64 stores
  const int bb = bh >> 4, h = bh & 15;
#pragma unroll
  for (int mf = 0; mf < 2; ++mf) {
    float inv = 1.0f / l_run[mf];
    int nrow = q0 + mf*16 + col;
#pragma unroll
    for (int hf = 0; hf < 4; ++hf) {
      u16x4 pk;
#pragma unroll
      for (int j = 0; j < 4; ++j) pk[j] = f2bf(o[mf][hf][j] * inv);
      int feat = h*64 + hf*16 + kg*4;
      *(u16x4*)&ao[(size_t)(bb * SEQ + nrow) * D_MODEL + feat] = pk;
    }
  }
#undef LOAD_TILES
}

extern "C" void kernel_launch(void* const* d_in, const int* in_sizes, int n_in,
                              void* d_out, int out_size, void* d_ws, size_t ws_size,
                              hipStream_t stream)
{
  const float* x     = (const float*)d_in[0];
  const float* w_qkv = (const float*)d_in[1];
  const float* b_qkv = (const float*)d_in[2];
  const float* w_out = (const float*)d_in[3];
  const float* b_out = (const float*)d_in[4];
  float* out = (float*)d_out;
  (void)in_sizes; (void)n_in; (void)out_size; (void)ws_size;

  char* ws = (char*)d_ws;
  u16* x_bf   = (u16*)(ws);                        //  0-8   [4096][1024]
  u16* wqkv_t = (u16*)(ws + (size_t)( 8 << 20));   //  8-14  [3072][1024]
  u16* wout_t = (u16*)(ws + (size_t)(14 << 20));   // 14-16  [1024][1024]
  u16* qb     = (u16*)(ws + (size_t)(16 << 20));   // 16-24  [32][2048][64]
  u16* kb     = (u16*)(ws + (size_t)(24 << 20));   // 24-32
  u16* vt     = (u16*)(ws + (size_t)(32 << 20));   // 32-40  [32][64][2048]
  u16* ao     = (u16*)(ws + (size_t)(40 << 20));   // 40-48  [4096][1024]

  prep_kernel<<<2048 + 3072 + 1024, 256, 0, stream>>>(x, w_qkv, w_out, x_bf, wqkv_t, wout_t);

  gemm_bt_kernel<0><<<(MTOK/128)*(3072/128), 256, 0, stream>>>(
      x_bf, wqkv_t, b_qkv, nullptr, qb, kb, vt, MTOK, 3072, 1024);

  attn_kernel<<<32*16, 256, 0, stream>>>(qb, kb, vt, ao);

  gemm_bt_kernel<1><<<(MTOK/128)*(1024/128), 256, 0, stream>>>(
      ao, wout_t, b_out, out, nullptr, nullptr, nullptr, MTOK, 1024, 1024);
}